// Round 6
// baseline (125.125 us; speedup 1.0000x reference)
//
#include <hip/hip_runtime.h>

#define B_DIM 256
#define IN_DIM 512
#define OUT_DIM 1024

typedef __attribute__((__ext_vector_type__(2))) float v2f;

// ---------- spike bits (exact 0.0/1.0 floats) -> fp8 byte value ----------
// byte = s<<7|e3<<6|e2<<5|e1<<4|e0<<3|m2<<2|m1<<1|m0 via exact f32 FMA tree.
__device__ __forceinline__ unsigned fbyte(float4 a, float4 b) {
    float t1 = __builtin_fmaf(a.x, 2.0f, a.y);   // s*2 + e3
    float t2 = __builtin_fmaf(a.z, 2.0f, a.w);   // e2*2 + e1
    float t3 = __builtin_fmaf(b.x, 2.0f, b.y);   // e0*2 + m2
    float t4 = __builtin_fmaf(b.z, 2.0f, b.w);   // m1*2 + m0
    float u1 = __builtin_fmaf(t1, 4.0f, t2);
    float u2 = __builtin_fmaf(t3, 4.0f, t4);
    return (unsigned)__builtin_fmaf(u1, 16.0f, u2);
}

// ---------- encode fp32 (exact E4M3) -> [8] spike bits ----------
__device__ __forceinline__ void store8(float* __restrict__ out, int idx, float v) {
    unsigned au = __float_as_uint(v) & 0x7fffffffu;
    float sgn = (v < 0.0f) ? 1.0f : 0.0f;           // -0.0 -> sign bit 0, like ref
    int ef, man;
    if (au >= 0x3c800000u) {                         // |v| >= 2^-6 : normal
        ef  = (int)(au >> 23) - 120;                 // (exp-127)+7
        man = (int)((au >> 20) & 7u);
    } else {                                         // subnormal / zero
        ef  = 0;
        man = (int)(__uint_as_float(au) * 512.0f);   // exact multiple of 2^-9
    }
    float4 lo = make_float4(sgn,
                            (float)((ef >> 3) & 1), (float)((ef >> 2) & 1),
                            (float)((ef >> 1) & 1));
    float4 hi = make_float4((float)(ef & 1),
                            (float)((man >> 2) & 1), (float)((man >> 1) & 1),
                            (float)(man & 1));
    float4* op = (float4*)(out + (size_t)idx * 8);
    op[0] = lo;
    op[1] = hi;
}

// quantize both lanes of a v2f to exact E4M3 values (RNE, saturating)
__device__ __forceinline__ v2f qpk(v2f v) {
    int q = __builtin_amdgcn_cvt_pk_fp8_f32(v.x, v.y, 0, false);
    return __builtin_amdgcn_cvt_pk_f32_fp8(q, false);
}

struct F8 { float4 v[8]; };
__device__ __forceinline__ F8 ld8(const float4* __restrict__ p) {
    F8 r;
#pragma unroll
    for (int j = 0; j < 8; ++j) r.v[j] = p[j];
    return r;
}
__device__ __forceinline__ unsigned pack4(const F8& f) {
    unsigned b0 = fbyte(f.v[0], f.v[1]);
    unsigned b1 = fbyte(f.v[2], f.v[3]);
    unsigned b2 = fbyte(f.v[4], f.v[5]);
    unsigned b3 = fbyte(f.v[6], f.v[7]);
    return b0 | (b1 << 8) | (b2 << 16) | (b3 << 24);
}

// ---------- fused decode + sequential-quantized accumulation (ws-free) ----
// grid 256 x 512 threads. block = o-stripe 32 x b-group 32.
//   stripe = bid & 31 -> bid%8 = stripe%8: all 8 blocks of a stripe share an
//   XCD (round-robin dispatch) -> stripe's raw W stays in that XCD's L2.
// Decode: 16 chunks/thread (8 W + 8 X), each 8 contiguous float4 (128 B),
//   software-pipelined depth-1 (load chunk c+1 while packing chunk c) ->
//   ~8 loads in flight/lane (round-5 had ~1: VGPR=36, latency-serialized).
// LDS (34.3 KB, padded strides -> no runtime swizzle math):
//   lw[i4*33 + ol]  u32 = 4 consecutive-i fp8 bytes of w-row ol
//     write: lanes vary i4, bank (i4+ol)%32 -> 2/bank (free)
//     read:  fixed i4, lane ol -> permutation (free)
//   lx[i4*34 + rr]  u32 = 4 consecutive-i fp8 bytes of x-row rr
//     write: (2*i4+rr)%32 -> 4-way, one-time; read: b64 broadcast (free)
__global__ __launch_bounds__(512, 2) void k_fused(const float* __restrict__ xbits,
                                                  const float* __restrict__ wbits,
                                                  float* __restrict__ out) {
    __shared__ unsigned lw[128 * 33];              // 16.5 KB
    __shared__ unsigned lx[128 * 34];              // 17.0 KB

    int tid    = threadIdx.x;
    int lane   = tid & 63;
    int w      = tid >> 6;                         // wave 0..7
    int bid    = blockIdx.x;
    int stripe = bid & 31;                         // o-stripe (32 outputs)
    int grp    = bid >> 5;                         // b-group (32 rows)

    int trow = tid >> 7;                           // 0..3
    int ti4  = tid & 127;                          // 0..127
    const float4* wp0 = (const float4*)wbits +
        ((size_t)(stripe * 32 + trow) * IN_DIM + ti4 * 4) * 2;
    const float4* xp0 = (const float4*)xbits +
        ((size_t)(grp * 32 + trow) * IN_DIM + ti4 * 4) * 2;
    int lwoff = ti4 * 33 + trow;                   // + c*4 per chunk
    int lxoff = ti4 * 34 + trow;                   // + c*4 per chunk

    // ---- pipelined decode: chunk c covers rows {trow + c*4}, i-quad ti4
    F8 A = ld8(wp0);
#pragma unroll
    for (int c = 0; c < 16; ++c) {
        F8 N = A;
        if (c < 15) {
            int cn = c + 1;
            const float4* pn = (cn < 8) ? wp0 + (size_t)cn * 4096
                                        : xp0 + (size_t)(cn - 8) * 4096;
            N = ld8(pn);
        }
        unsigned u = pack4(A);
        if (c < 8) lw[lwoff + c * 4] = u;
        else       lx[lxoff + (c - 8) * 4] = u;
        A = N;
    }
    __syncthreads();

    int ol = lane & 31;                            // output column in stripe
    int p  = w * 2 + (lane >> 5);                  // b-pair 0..15
    const unsigned* lwb = lw + ol;                 // [i4] at i4*33
    const unsigned* lxb = lx + 2 * p;              // b64 at i4*34
    v2f acc = {0.0f, 0.0f};                        // q(0 + p0) == p0: safe init

#pragma unroll 8
    for (int i4 = 0; i4 < 128; ++i4) {
        unsigned wd = lwb[i4 * 33];
        uint2 xr = *(const uint2*)(lxb + i4 * 34); // {row r0 bytes, row r1 bytes}
        // re-pair rows for the packed chains: m0={r0i0,r1i0,r0i1,r1i1}, m1=i2,i3
        unsigned m0 = __builtin_amdgcn_perm(xr.y, xr.x, 0x05010400u);
        unsigned m1 = __builtin_amdgcn_perm(xr.y, xr.x, 0x07030602u);
        v2f w01 = __builtin_amdgcn_cvt_pk_f32_fp8((int)wd, false);
        v2f w23 = __builtin_amdgcn_cvt_pk_f32_fp8((int)wd, true);
        v2f x0  = __builtin_amdgcn_cvt_pk_f32_fp8((int)m0, false);
        v2f x1  = __builtin_amdgcn_cvt_pk_f32_fp8((int)m0, true);
        v2f x2  = __builtin_amdgcn_cvt_pk_f32_fp8((int)m1, false);
        v2f x3  = __builtin_amdgcn_cvt_pk_f32_fp8((int)m1, true);
        acc = qpk(acc + qpk(x0 * (v2f){w01.x, w01.x}));
        acc = qpk(acc + qpk(x1 * (v2f){w01.y, w01.y}));
        acc = qpk(acc + qpk(x2 * (v2f){w23.x, w23.x}));
        acc = qpk(acc + qpk(x3 * (v2f){w23.y, w23.y}));
    }

    int og = stripe * 32 + ol;
    int b0 = grp * 32 + 2 * p;
    store8(out, (size_t)b0 * OUT_DIM + og, acc.x);
    store8(out, (size_t)(b0 + 1) * OUT_DIM + og, acc.y);
}

extern "C" void kernel_launch(void* const* d_in, const int* in_sizes, int n_in,
                              void* d_out, int out_size, void* d_ws, size_t ws_size,
                              hipStream_t stream) {
    const float* xb = (const float*)d_in[0];   // [256][512][8]
    const float* wb = (const float*)d_in[1];   // [1024][512][8]
    float* out = (float*)d_out;                // [256][1024][8]
    (void)d_ws; (void)ws_size;                 // deliberately unused (no ws poison)

    k_fused<<<dim3(256), dim3(512), 0, stream>>>(xb, wb, out);
}